// Round 3
// baseline (657.490 us; speedup 1.0000x reference)
//
#include <hip/hip_runtime.h>
#include <hip/hip_cooperative_groups.h>
#include <hip/hip_bf16.h>
#include <cstdint>
#include <cstddef>

namespace cg = cooperative_groups;

#define N_NODES 10000
#define M_PAD   10240   // 80 panels of 128
#define HEADS   4
#define NBLK    320

typedef __bf16 bfrag8 __attribute__((ext_vector_type(8)));
typedef __bf16 bfrag2 __attribute__((ext_vector_type(2)));
typedef float  floatx4 __attribute__((ext_vector_type(4)));
typedef float  floatx2 __attribute__((ext_vector_type(2)));

#define S0V (M_PAD * 512 / 8)   // xb
#define S1E (512 * 512 / 8)     // W1T
#define S2E (512 * 512 / 8)     // W2T
#define S3E (512 * 128 / 8)     // W3T
#define S4E (128 * 256 / 8)     // WlT
#define S5E (512 * 256 / 8)     // WrT

struct Params {
    const float *x, *W1, *W2, *W3, *Wl, *Wr;
    const float *a1s, *a1d, *b1, *a2s, *a2d, *b2, *a3s, *a3d, *b3, *bl, *br;
    const int *esrc, *edst; int E;
    __bf16 *xb, *hb, *hb3;
    unsigned char *Hi8;
    __bf16 *W1T, *W2T, *W3T, *WlT, *WrT;
    float *esp, *edp;
    int *deg, *rowptr, *cursor, *csr, *blksum, *blkoff;
    float *out;
};

// ---------------- MFMA GEMM K-loop, BK=64, tile 128(M) x 16*NT(N) ----------------

template <int NT>
__device__ __forceinline__ void gemm_loop(const __bf16* __restrict__ A,
                                          const __bf16* __restrict__ BT, int K,
                                          int m0, int n0, int wave, int lane,
                                          __bf16* As, __bf16* Bs,
                                          floatx4 (&acc)[2][NT]) {
    int r = wave * 8 + (lane >> 3);          // 0..31 staging row
    int kof = (lane & 7) * 8;
    const __bf16* gA = A + (size_t)(m0 + r) * K + kof;
    const __bf16* gB = BT + (size_t)(n0 + r) * K + kof;
    __bf16* lA = As + r * 64 + kof;
    __bf16* lB = Bs + r * 64 + kof;
    const __bf16* fA = As + (wave * 32 + (lane & 15)) * 64 + (lane >> 4) * 8;
    const __bf16* fB = Bs + (lane & 15) * 64 + (lane >> 4) * 8;

    for (int k0 = 0; k0 < K; k0 += 64) {
#pragma unroll
        for (int u = 0; u < 4; ++u)
            __builtin_amdgcn_global_load_lds(
                (const __attribute__((address_space(1))) void*)(gA + (size_t)u * 32 * K),
                (__attribute__((address_space(3))) void*)(lA + u * 32 * 64), 16, 0, 0);
#pragma unroll
        for (int u = 0; u < NT / 2; ++u)
            __builtin_amdgcn_global_load_lds(
                (const __attribute__((address_space(1))) void*)(gB + (size_t)u * 32 * K),
                (__attribute__((address_space(3))) void*)(lB + u * 32 * 64), 16, 0, 0);
        gA += 64; gB += 64;
        __syncthreads();

#pragma unroll
        for (int ks = 0; ks < 2; ++ks) {
            bfrag8 a0 = *(const bfrag8*)(fA + ks * 32);
            bfrag8 a1 = *(const bfrag8*)(fA + 16 * 64 + ks * 32);
#pragma unroll
            for (int nt = 0; nt < NT; ++nt) {
                bfrag8 b = *(const bfrag8*)(fB + nt * 16 * 64 + ks * 32);
                acc[0][nt] = __builtin_amdgcn_mfma_f32_16x16x32_bf16(a0, b, acc[0][nt], 0, 0, 0);
                acc[1][nt] = __builtin_amdgcn_mfma_f32_16x16x32_bf16(a1, b, acc[1][nt], 0, 0, 0);
            }
        }
        __syncthreads();
    }
}

// one 128x128 tile of H = A@B^T, fp8 out + fused logit sums (full head per tile)
__device__ __forceinline__ void gemm_h_tile(const __bf16* __restrict__ A,
                                            const __bf16* __restrict__ BT,
                                            unsigned char* __restrict__ C8,
                                            int N, int K, int H,
                                            const float* __restrict__ as_,
                                            const float* __restrict__ ad_,
                                            float* __restrict__ esp,
                                            float* __restrict__ edp,
                                            int t, char* smem, int wave, int lane) {
    __bf16* As = (__bf16*)smem;
    __bf16* Bs = (__bf16*)(smem + 16384);
    int px = t % 80, py = t / 80;
    int m0 = px * 128, n0 = py * 128;
    floatx4 acc[2][8] = {};
    gemm_loop<8>(A, BT, K, m0, n0, wave, lane, As, Bs, acc);

    int crow = m0 + wave * 32 + (lane >> 4) * 4;
    int ccol = n0 + (lane & 15);
#pragma unroll
    for (int mt = 0; mt < 2; ++mt)
#pragma unroll
        for (int nt = 0; nt < 8; ++nt)
#pragma unroll
            for (int r = 0; r < 4; ++r) {
                float v = acc[mt][nt][r];
                size_t o = (size_t)(crow + mt * 16 + r) * N + ccol + nt * 16;
                int p = __builtin_amdgcn_cvt_pk_fp8_f32(v, v, 0, false);
                C8[o] = (unsigned char)(p & 0xff);
            }

    int head = n0 >> 7;
    float a_sv[8], a_dv[8];
#pragma unroll
    for (int nt = 0; nt < 8; ++nt) {
        int cin = nt * 16 + (lane & 15);
        a_sv[nt] = as_[head * 128 + cin];
        a_dv[nt] = ad_[head * 128 + cin];
    }
#pragma unroll
    for (int mt = 0; mt < 2; ++mt)
#pragma unroll
        for (int r = 0; r < 4; ++r) {
            float ps = 0.f, pd = 0.f;
#pragma unroll
            for (int nt = 0; nt < 8; ++nt) {
                float v = acc[mt][nt][r];
                ps += v * a_sv[nt];
                pd += v * a_dv[nt];
            }
#pragma unroll
            for (int off = 8; off; off >>= 1) {
                ps += __shfl_xor(ps, off);
                pd += __shfl_xor(pd, off);
            }
            if ((lane & 15) == 0) {
                int row = crow + mt * 16 + r;
                esp[row * H + head] = ps;
                edp[row * H + head] = pd;
            }
        }
}

// one 128x64 tile of final: C = A1@B1T^T + A2@B2T^T + bias1 + bias2
__device__ __forceinline__ void gemm_final_tile(const __bf16* __restrict__ A1,
                                                const __bf16* __restrict__ B1T, int K1,
                                                const __bf16* __restrict__ A2,
                                                const __bf16* __restrict__ B2T, int K2,
                                                float* __restrict__ C,
                                                const float* __restrict__ bias1,
                                                const float* __restrict__ bias2,
                                                int M, int N,
                                                int t, char* smem, int wave, int lane) {
    __bf16* As = (__bf16*)smem;
    __bf16* Bs = (__bf16*)(smem + 16384);
    int px = t % 80, py = t / 80;
    int m0 = px * 128, n0 = py * 64;
    floatx4 acc[2][4] = {};
    gemm_loop<4>(A1, B1T, K1, m0, n0, wave, lane, As, Bs, acc);
    gemm_loop<4>(A2, B2T, K2, m0, n0, wave, lane, As, Bs, acc);

    int crow = m0 + wave * 32 + (lane >> 4) * 4;
    int ccol = n0 + (lane & 15);
#pragma unroll
    for (int mt = 0; mt < 2; ++mt)
#pragma unroll
        for (int nt = 0; nt < 4; ++nt)
#pragma unroll
            for (int r = 0; r < 4; ++r) {
                int row = crow + mt * 16 + r;
                int col = ccol + nt * 16;
                if (row < M)
                    C[(size_t)row * N + col] = acc[mt][nt][r] + bias1[col] + bias2[col];
            }
}

// ---------------- fused softmax + weighted gather for one node ----------------

template <int H>
__device__ __forceinline__ void gather_node(const unsigned char* __restrict__ H8,
                                            const float* __restrict__ esp,
                                            const float* __restrict__ edp,
                                            const int* __restrict__ rowptr,
                                            const int* __restrict__ csr,
                                            const float* __restrict__ bias,
                                            __bf16* __restrict__ outb,
                                            int node, int wave, int lane,
                                            int* sIdx, float* sWgt) {
    constexpr int F = H * 128;
    constexpr int CH = F / 64;          // 8 or 2
    __bf16* op = outb + (size_t)node * F + lane * CH;
    if (node >= N_NODES) {
        if (H == 4) { bfrag8 z = {}; *(bfrag8*)op = z; }
        else        { bfrag2 z = {}; *(bfrag2*)op = z; }
        return;
    }
    int hsel = (H == 4) ? (lane >> 4) : 0;
    const unsigned char* hp = H8 + lane * CH;
    int beg = rowptr[node], end = rowptr[node + 1];
    float acc[CH] = {};
    float wsum = 0.f;

    float edv0 = 0.f, edv1 = 0.f, edv2 = 0.f, edv3 = 0.f;
    if (H == 4) {
        float4 e4 = *(const float4*)(edp + node * 4);
        edv0 = e4.x; edv1 = e4.y; edv2 = e4.z; edv3 = e4.w;
    } else {
        edv0 = edp[node];
    }

    int* wIdx = sIdx + wave * 64;
    float* wW  = sWgt + wave * 64 * H;

    for (int t0 = beg; t0 < end; t0 += 64) {
        int n_t = end - t0; if (n_t > 64) n_t = 64;
        // pass 1: one lane per edge, all H logits once
        if (lane < n_t) {
            int s = csr[t0 + lane];
            wIdx[lane] = s;
            if (H == 4) {
                float4 es = *(const float4*)(esp + s * 4);
                float tt0 = es.x + edv0; tt0 = tt0 > 0.f ? tt0 : 0.2f * tt0;
                float tt1 = es.y + edv1; tt1 = tt1 > 0.f ? tt1 : 0.2f * tt1;
                float tt2 = es.z + edv2; tt2 = tt2 > 0.f ? tt2 : 0.2f * tt2;
                float tt3 = es.w + edv3; tt3 = tt3 > 0.f ? tt3 : 0.2f * tt3;
                floatx4 w4 = { __expf(tt0), __expf(tt1), __expf(tt2), __expf(tt3) };
                *(floatx4*)&wW[lane * 4] = w4;
            } else {
                float tt = esp[s] + edv0; tt = tt > 0.f ? tt : 0.2f * tt;
                wW[lane] = __expf(tt);
            }
        }
        asm volatile("s_waitcnt lgkmcnt(0)" ::: "memory");

        // pass 2: weighted gather, 4-deep pipelined
        int e = 0;
        for (; e + 3 < n_t; e += 4) {
            int s4[4]; float w4[4];
#pragma unroll
            for (int u = 0; u < 4; ++u) {
                s4[u] = wIdx[e + u];
                w4[u] = wW[(e + u) * H + hsel];
            }
            if (H == 4) {
                uint2 p4[4];
#pragma unroll
                for (int u = 0; u < 4; ++u) p4[u] = *(const uint2*)(hp + (size_t)s4[u] * F);
#pragma unroll
                for (int u = 0; u < 4; ++u) {
                    float wgt = w4[u];
                    wsum += wgt;
                    floatx2 f0 = __builtin_amdgcn_cvt_pk_f32_fp8(p4[u].x, false);
                    floatx2 f1 = __builtin_amdgcn_cvt_pk_f32_fp8(p4[u].x, true);
                    floatx2 f2 = __builtin_amdgcn_cvt_pk_f32_fp8(p4[u].y, false);
                    floatx2 f3 = __builtin_amdgcn_cvt_pk_f32_fp8(p4[u].y, true);
                    acc[0] += wgt * f0[0]; acc[1] += wgt * f0[1];
                    acc[2] += wgt * f1[0]; acc[3] += wgt * f1[1];
                    acc[4] += wgt * f2[0]; acc[5] += wgt * f2[1];
                    acc[6] += wgt * f3[0]; acc[7] += wgt * f3[1];
                }
            } else {
                unsigned short p4[4];
#pragma unroll
                for (int u = 0; u < 4; ++u) p4[u] = *(const unsigned short*)(hp + (size_t)s4[u] * F);
#pragma unroll
                for (int u = 0; u < 4; ++u) {
                    float wgt = w4[u];
                    wsum += wgt;
                    floatx2 f0 = __builtin_amdgcn_cvt_pk_f32_fp8((int)p4[u], false);
                    acc[0] += wgt * f0[0]; acc[1] += wgt * f0[1];
                }
            }
        }
        for (; e < n_t; ++e) {
            int s0 = wIdx[e];
            float wgt = wW[e * H + hsel];
            wsum += wgt;
            if (H == 4) {
                uint2 p = *(const uint2*)(hp + (size_t)s0 * F);
                floatx2 f0 = __builtin_amdgcn_cvt_pk_f32_fp8(p.x, false);
                floatx2 f1 = __builtin_amdgcn_cvt_pk_f32_fp8(p.x, true);
                floatx2 f2 = __builtin_amdgcn_cvt_pk_f32_fp8(p.y, false);
                floatx2 f3 = __builtin_amdgcn_cvt_pk_f32_fp8(p.y, true);
                acc[0] += wgt * f0[0]; acc[1] += wgt * f0[1];
                acc[2] += wgt * f1[0]; acc[3] += wgt * f1[1];
                acc[4] += wgt * f2[0]; acc[5] += wgt * f2[1];
                acc[6] += wgt * f3[0]; acc[7] += wgt * f3[1];
            } else {
                unsigned short p = *(const unsigned short*)(hp + (size_t)s0 * F);
                floatx2 f0 = __builtin_amdgcn_cvt_pk_f32_fp8((int)p, false);
                acc[0] += wgt * f0[0]; acc[1] += wgt * f0[1];
            }
        }
    }

    float inv = 1.f / (wsum + 1e-16f);
    if (H == 4) {
        bfrag8 r;
#pragma unroll
        for (int k = 0; k < 8; ++k) {
            float o = acc[k] * inv + bias[lane * 8 + k];
            o = o > 0.f ? o : __expf(o) - 1.f;     // ELU
            r[k] = (__bf16)o;
        }
        *(bfrag8*)op = r;
    } else {
        bfrag2 r;
#pragma unroll
        for (int k = 0; k < 2; ++k) {
            float o = acc[k] * inv + bias[lane * 2 + k];
            o = o > 0.f ? o : __expf(o) - 1.f;
            r[k] = (__bf16)o;
        }
        *(bfrag2*)op = r;
    }
}

// ---------------- persistent cooperative mega-kernel: 12 phases, 11 grid syncs ----

__global__ __launch_bounds__(256, 2) void mega(Params P) {
    __shared__ __align__(16) char smem[32768];
    __shared__ int wtot[4], woff[4];
    cg::grid_group grid = cg::this_grid();
    int tid = threadIdx.x, bid = blockIdx.x;
    int wave = tid >> 6, lane = tid & 63;
    int nth = gridDim.x * 256;
    int gtid = bid * 256 + tid;
    int* sIdx = (int*)smem;
    float* sWgt = (float*)(smem + 4096);

    // ---- A: prep (bf16 pad + 5 transposes + degree count) ----
    {
        int sp_total = S0V + S1E + S2E + S3E + S4E + S5E + P.E;
        for (int it = gtid; it < sp_total; it += nth) {
            int i = it;
            if (i < S0V) {
                int base = i * 8;
                int row = base >> 9;
                bfrag8 r = {};
                if (row < N_NODES) {
                    float4 f0 = ((const float4*)P.x)[i * 2];
                    float4 f1 = ((const float4*)P.x)[i * 2 + 1];
                    r[0] = (__bf16)f0.x; r[1] = (__bf16)f0.y; r[2] = (__bf16)f0.z; r[3] = (__bf16)f0.w;
                    r[4] = (__bf16)f1.x; r[5] = (__bf16)f1.y; r[6] = (__bf16)f1.z; r[7] = (__bf16)f1.w;
                }
                *(bfrag8*)(P.xb + base) = r;
            } else if ((i -= S0V) < S1E) {
                int n = i & 511, kb = (i >> 9) * 8;
                bfrag8 r;
#pragma unroll
                for (int t = 0; t < 8; ++t) r[t] = (__bf16)P.W1[(kb + t) * 512 + n];
                *(bfrag8*)(P.W1T + n * 512 + kb) = r;
            } else if ((i -= S1E) < S2E) {
                int n = i & 511, kb = (i >> 9) * 8;
                bfrag8 r;
#pragma unroll
                for (int t = 0; t < 8; ++t) r[t] = (__bf16)P.W2[(kb + t) * 512 + n];
                *(bfrag8*)(P.W2T + n * 512 + kb) = r;
            } else if ((i -= S2E) < S3E) {
                int n = i & 127, kb = (i >> 7) * 8;
                bfrag8 r;
#pragma unroll
                for (int t = 0; t < 8; ++t) r[t] = (__bf16)P.W3[(kb + t) * 128 + n];
                *(bfrag8*)(P.W3T + n * 512 + kb) = r;
            } else if ((i -= S3E) < S4E) {
                int n = i & 255, kb = (i >> 8) * 8;
                bfrag8 r;
#pragma unroll
                for (int t = 0; t < 8; ++t) r[t] = (__bf16)P.Wl[(kb + t) * 256 + n];
                *(bfrag8*)(P.WlT + n * 128 + kb) = r;
            } else if ((i -= S4E) < S5E) {
                int n = i & 255, kb = (i >> 8) * 8;
                bfrag8 r;
#pragma unroll
                for (int t = 0; t < 8; ++t) r[t] = (__bf16)P.Wr[(kb + t) * 256 + n];
                *(bfrag8*)(P.WrT + n * 512 + kb) = r;
            } else if ((i -= S5E) < P.E) {
                atomicAdd(&P.deg[P.edst[i]], 1);
            }
        }
    }
    grid.sync();

    // ---- B1: per-block scan of deg+1 (40 blocks x 256 nodes); lex persists in regs ----
    int lex = 0, myi = 0x7fffffff;
    if (bid < 40) {
        int i = bid * 256 + tid; myi = i;
        int s = (i < N_NODES) ? P.deg[i] + 1 : 0;
        int v = s;
#pragma unroll
        for (int off = 1; off < 64; off <<= 1) {
            int o = __shfl_up(v, off);
            if (lane >= off) v += o;
        }
        if (lane == 63) wtot[wave] = v;
        __syncthreads();
        if (tid == 0) {
            int r = 0;
#pragma unroll
            for (int w2 = 0; w2 < 4; ++w2) { woff[w2] = r; r += wtot[w2]; }
            P.blksum[bid] = r;
        }
        __syncthreads();
        lex = woff[wave] + v - s;
    }
    grid.sync();

    // ---- B2: block 0 scans the 40 block sums ----
    if (bid == 0 && wave == 0) {
        int t = (lane < 40) ? P.blksum[lane] : 0;
        int v = t;
#pragma unroll
        for (int off = 1; off < 64; off <<= 1) {
            int o = __shfl_up(v, off);
            if (lane >= off) v += o;
        }
        if (lane < 40) P.blkoff[lane] = v - t;
        if (lane == 39) P.rowptr[N_NODES] = v;
    }
    grid.sync();

    // ---- B3: write rowptr/cursor ----
    if (myi < N_NODES) {
        int off = P.blkoff[bid] + lex;
        P.rowptr[myi] = off;
        P.cursor[myi] = off;
    }
    grid.sync();

    // ---- C: scatter edges into CSR ----
    for (int i = gtid; i < P.E + N_NODES; i += nth) {
        if (i < P.E) {
            int pos = atomicAdd(&P.cursor[P.edst[i]], 1);
            P.csr[pos] = P.esrc[i];
        } else {
            int v = i - P.E;
            int pos = atomicAdd(&P.cursor[v], 1);
            P.csr[pos] = v;
        }
    }
    grid.sync();

    // ---- D: gemm layer 1 (320 tiles) ----
    for (int t = bid; t < 320; t += gridDim.x)
        gemm_h_tile(P.xb, P.W1T, P.Hi8, 512, 512, 4, P.a1s, P.a1d, P.esp, P.edp,
                    t, smem, wave, lane);
    grid.sync();

    // ---- E: gather layer 1 ----
    for (int g = bid; g < M_PAD / 4; g += gridDim.x)
        gather_node<4>(P.Hi8, P.esp, P.edp, P.rowptr, P.csr, P.b1, P.hb,
                       g * 4 + wave, wave, lane, sIdx, sWgt);
    grid.sync();

    // ---- F: gemm layer 2 ----
    for (int t = bid; t < 320; t += gridDim.x)
        gemm_h_tile(P.hb, P.W2T, P.Hi8, 512, 512, 4, P.a2s, P.a2d, P.esp, P.edp,
                    t, smem, wave, lane);
    grid.sync();

    // ---- G: gather layer 2 ----
    for (int g = bid; g < M_PAD / 4; g += gridDim.x)
        gather_node<4>(P.Hi8, P.esp, P.edp, P.rowptr, P.csr, P.b2, P.hb,
                       g * 4 + wave, wave, lane, sIdx, sWgt);
    grid.sync();

    // ---- H: gemm layer 3 (80 tiles, H=1, N=128) ----
    for (int t = bid; t < 80; t += gridDim.x)
        gemm_h_tile(P.hb, P.W3T, P.Hi8, 128, 512, 1, P.a3s, P.a3d, P.esp, P.edp,
                    t, smem, wave, lane);
    grid.sync();

    // ---- I: gather layer 3 ----
    for (int g = bid; g < M_PAD / 4; g += gridDim.x)
        gather_node<1>(P.Hi8, P.esp, P.edp, P.rowptr, P.csr, P.b3, P.hb3,
                       g * 4 + wave, wave, lane, sIdx, sWgt);
    grid.sync();

    // ---- J: fused residual + final linear (320 tiles) ----
    for (int t = bid; t < 320; t += gridDim.x)
        gemm_final_tile(P.xb, P.WrT, 512, P.hb3, P.WlT, 128, P.out, P.br, P.bl,
                        N_NODES, 256, t, smem, wave, lane);
}

// ---------------- launch ----------------

extern "C" void kernel_launch(void* const* d_in, const int* in_sizes, int n_in,
                              void* d_out, int out_size, void* d_ws, size_t ws_size,
                              hipStream_t stream) {
    Params P;
    P.x   = (const float*)d_in[0];
    P.W1  = (const float*)d_in[1];
    P.a1s = (const float*)d_in[2];
    P.a1d = (const float*)d_in[3];
    P.b1  = (const float*)d_in[4];
    P.W2  = (const float*)d_in[5];
    P.a2s = (const float*)d_in[6];
    P.a2d = (const float*)d_in[7];
    P.b2  = (const float*)d_in[8];
    P.W3  = (const float*)d_in[9];
    P.a3s = (const float*)d_in[10];
    P.a3d = (const float*)d_in[11];
    P.b3  = (const float*)d_in[12];
    P.Wl  = (const float*)d_in[13];
    P.bl  = (const float*)d_in[14];
    P.Wr  = (const float*)d_in[15];
    P.br  = (const float*)d_in[16];
    const int* ei = (const int*)d_in[17];
    P.E = in_sizes[17] / 2;
    P.esrc = ei;
    P.edst = ei + P.E;
    const int slots = P.E + N_NODES;
    P.out = (float*)d_out;

    char* w = (char*)d_ws;
    auto alloc = [&](size_t b) { char* p = w; w += (b + 255) & ~(size_t)255; return p; };
    P.xb  = (__bf16*)alloc((size_t)M_PAD * 512 * 2);
    P.hb  = (__bf16*)alloc((size_t)M_PAD * 512 * 2);
    P.hb3 = (__bf16*)alloc((size_t)M_PAD * 128 * 2);
    P.Hi8 = (unsigned char*)alloc((size_t)M_PAD * 512);
    P.W1T = (__bf16*)alloc(512 * 512 * 2);
    P.W2T = (__bf16*)alloc(512 * 512 * 2);
    P.W3T = (__bf16*)alloc(128 * 512 * 2);
    P.WlT = (__bf16*)alloc(256 * 128 * 2);
    P.WrT = (__bf16*)alloc(256 * 512 * 2);
    P.esp = (float*)alloc((size_t)M_PAD * HEADS * 4);
    P.edp = (float*)alloc((size_t)M_PAD * HEADS * 4);
    P.deg    = (int*)alloc(N_NODES * 4);
    P.rowptr = (int*)alloc((N_NODES + 1) * 4);
    P.cursor = (int*)alloc(N_NODES * 4);
    P.csr    = (int*)alloc((size_t)slots * 4);
    P.blksum = (int*)alloc(64 * 4);
    P.blkoff = (int*)alloc(64 * 4);

    (void)hipMemsetAsync(P.deg, 0, N_NODES * sizeof(int), stream);

    int nblk = NBLK;
    int maxb = 0;
    if (hipOccupancyMaxActiveBlocksPerMultiprocessor(&maxb, mega, 256, 0) == hipSuccess && maxb > 0) {
        int ncu = 0;
        if (hipDeviceGetAttribute(&ncu, hipDeviceAttributeMultiprocessorCount, 0) == hipSuccess && ncu > 0) {
            if (maxb * ncu < nblk) nblk = maxb * ncu;
        }
    }
    void* kargs[] = { (void*)&P };
    (void)hipLaunchCooperativeKernel((const void*)mega, dim3(nblk), dim3(256),
                                     kargs, 0, stream);
}

// Round 4
// 603.435 us; speedup vs baseline: 1.0896x; 1.0896x over previous
//
#include <hip/hip_runtime.h>
#include <hip/hip_bf16.h>
#include <cstdint>
#include <cstddef>

#define N_NODES 10000
#define M_PAD   10240   // 80 panels of 128; 80 % 8 == 0 -> panel%8 = XCD under round-robin
#define HEADS   4

typedef __bf16 bfrag8 __attribute__((ext_vector_type(8)));
typedef __bf16 bfrag2 __attribute__((ext_vector_type(2)));
typedef float  floatx4 __attribute__((ext_vector_type(4)));
typedef float  floatx2 __attribute__((ext_vector_type(2)));

#define S0V (M_PAD * 512 / 8)   // xb
#define S1E (512 * 512 / 8)     // W1T
#define S2E (512 * 512 / 8)     // W2T
#define S3E (512 * 128 / 8)     // W3T
#define S4E (128 * 256 / 8)     // WlT
#define S5E (512 * 256 / 8)     // WrT

// ---------------- prep: x->bf16 pad, 5 weight transposes, degree count;
// LAST block (done-counter) also performs the CSR scan -> saves a dispatch. ----

__global__ __launch_bounds__(256) void prep(const float* __restrict__ x,
                                            const float* __restrict__ W1,
                                            const float* __restrict__ W2,
                                            const float* __restrict__ W3,
                                            const float* __restrict__ Wl,
                                            const float* __restrict__ Wr,
                                            const int* __restrict__ edst, int E,
                                            __bf16* __restrict__ xb,
                                            __bf16* __restrict__ W1T,
                                            __bf16* __restrict__ W2T,
                                            __bf16* __restrict__ W3T,
                                            __bf16* __restrict__ WlT,
                                            __bf16* __restrict__ WrT,
                                            int* __restrict__ deg,
                                            int* __restrict__ rowptr,
                                            int* __restrict__ cursor,
                                            int* __restrict__ donecnt) {
    int i = blockIdx.x * 256 + threadIdx.x;
    if (i < S0V) {
        int base = i * 8;
        int row = base >> 9;
        bfrag8 r = {};
        if (row < N_NODES) {
            float4 f0 = ((const float4*)x)[i * 2];
            float4 f1 = ((const float4*)x)[i * 2 + 1];
            r[0] = (__bf16)f0.x; r[1] = (__bf16)f0.y; r[2] = (__bf16)f0.z; r[3] = (__bf16)f0.w;
            r[4] = (__bf16)f1.x; r[5] = (__bf16)f1.y; r[6] = (__bf16)f1.z; r[7] = (__bf16)f1.w;
        }
        *(bfrag8*)(xb + base) = r;
    } else if ((i -= S0V) < S1E) {          // W1: K=512, N=512
        int n = i & 511, kb = (i >> 9) * 8;
        bfrag8 r;
#pragma unroll
        for (int t = 0; t < 8; ++t) r[t] = (__bf16)W1[(kb + t) * 512 + n];
        *(bfrag8*)(W1T + n * 512 + kb) = r;
    } else if ((i -= S1E) < S2E) {          // W2
        int n = i & 511, kb = (i >> 9) * 8;
        bfrag8 r;
#pragma unroll
        for (int t = 0; t < 8; ++t) r[t] = (__bf16)W2[(kb + t) * 512 + n];
        *(bfrag8*)(W2T + n * 512 + kb) = r;
    } else if ((i -= S2E) < S3E) {          // W3: K=512, N=128
        int n = i & 127, kb = (i >> 7) * 8;
        bfrag8 r;
#pragma unroll
        for (int t = 0; t < 8; ++t) r[t] = (__bf16)W3[(kb + t) * 128 + n];
        *(bfrag8*)(W3T + n * 512 + kb) = r;
    } else if ((i -= S3E) < S4E) {          // Wl: K=128, N=256
        int n = i & 255, kb = (i >> 8) * 8;
        bfrag8 r;
#pragma unroll
        for (int t = 0; t < 8; ++t) r[t] = (__bf16)Wl[(kb + t) * 256 + n];
        *(bfrag8*)(WlT + n * 128 + kb) = r;
    } else if ((i -= S4E) < S5E) {          // Wr: K=512, N=256
        int n = i & 255, kb = (i >> 8) * 8;
        bfrag8 r;
#pragma unroll
        for (int t = 0; t < 8; ++t) r[t] = (__bf16)Wr[(kb + t) * 256 + n];
        *(bfrag8*)(WrT + n * 512 + kb) = r;
    } else if ((i -= S5E) < E) {
        atomicAdd(&deg[edst[i]], 1);
    }

    // ---- last finishing block runs the scan (no spin: everyone else is done) ----
    __threadfence();
    __shared__ int amLast;
    if (threadIdx.x == 0) {
        int prev = __hip_atomic_fetch_add(donecnt, 1, __ATOMIC_ACQ_REL,
                                          __HIP_MEMORY_SCOPE_AGENT);
        amLast = (prev == (int)gridDim.x - 1);
    }
    __syncthreads();
    if (!amLast) return;

    __shared__ int wtot[4], woff[4];
    int t = threadIdx.x, lane = t & 63, wv = t >> 6;
    const int chunk = (N_NODES + 255) / 256;   // 40
    int beg = t * chunk, end = beg + chunk;
    if (end > N_NODES) end = N_NODES;
    if (beg > N_NODES) beg = N_NODES;
    int s = 0;
    for (int j = beg; j < end; ++j)
        s += __hip_atomic_load(&deg[j], __ATOMIC_RELAXED, __HIP_MEMORY_SCOPE_AGENT) + 1;
    int v = s;
#pragma unroll
    for (int off = 1; off < 64; off <<= 1) {
        int o = __shfl_up(v, off);
        if (lane >= off) v += o;
    }
    if (lane == 63) wtot[wv] = v;
    __syncthreads();
    if (t == 0) {
        int r = 0;
#pragma unroll
        for (int w2 = 0; w2 < 4; ++w2) { woff[w2] = r; r += wtot[w2]; }
        rowptr[N_NODES] = r;
    }
    __syncthreads();
    int off = woff[wv] + v - s;
    for (int j = beg; j < end; ++j) {
        rowptr[j] = off; cursor[j] = off;
        off += __hip_atomic_load(&deg[j], __ATOMIC_RELAXED, __HIP_MEMORY_SCOPE_AGENT) + 1;
    }
}

// ---------------- MFMA GEMM K-loop, BK=64, tile 128(M) x 16*NT(N) ----------------

template <int NT>
__device__ __forceinline__ void gemm_loop(const __bf16* __restrict__ A,
                                          const __bf16* __restrict__ BT, int K,
                                          int m0, int n0, int wave, int lane,
                                          __bf16* As, __bf16* Bs,
                                          floatx4 (&acc)[2][NT]) {
    int r = wave * 8 + (lane >> 3);          // 0..31 staging row
    int kof = (lane & 7) * 8;
    const __bf16* gA = A + (size_t)(m0 + r) * K + kof;
    const __bf16* gB = BT + (size_t)(n0 + r) * K + kof;
    __bf16* lA = As + r * 64 + kof;
    __bf16* lB = Bs + r * 64 + kof;
    const __bf16* fA = As + (wave * 32 + (lane & 15)) * 64 + (lane >> 4) * 8;
    const __bf16* fB = Bs + (lane & 15) * 64 + (lane >> 4) * 8;

    for (int k0 = 0; k0 < K; k0 += 64) {
#pragma unroll
        for (int u = 0; u < 4; ++u)
            __builtin_amdgcn_global_load_lds(
                (const __attribute__((address_space(1))) void*)(gA + (size_t)u * 32 * K),
                (__attribute__((address_space(3))) void*)(lA + u * 32 * 64), 16, 0, 0);
#pragma unroll
        for (int u = 0; u < NT / 2; ++u)
            __builtin_amdgcn_global_load_lds(
                (const __attribute__((address_space(1))) void*)(gB + (size_t)u * 32 * K),
                (__attribute__((address_space(3))) void*)(lB + u * 32 * 64), 16, 0, 0);
        gA += 64; gB += 64;
        __syncthreads();

#pragma unroll
        for (int ks = 0; ks < 2; ++ks) {
            bfrag8 a0 = *(const bfrag8*)(fA + ks * 32);
            bfrag8 a1 = *(const bfrag8*)(fA + 16 * 64 + ks * 32);
#pragma unroll
            for (int nt = 0; nt < NT; ++nt) {
                bfrag8 b = *(const bfrag8*)(fB + nt * 16 * 64 + ks * 32);
                acc[0][nt] = __builtin_amdgcn_mfma_f32_16x16x32_bf16(a0, b, acc[0][nt], 0, 0, 0);
                acc[1][nt] = __builtin_amdgcn_mfma_f32_16x16x32_bf16(a1, b, acc[1][nt], 0, 0, 0);
            }
        }
        __syncthreads();
    }
}

// one 128x128 tile of H = A@B^T, fp8 out + fused logit sums (full head per tile)
__device__ __forceinline__ void gemm_h_tile(const __bf16* __restrict__ A,
                                            const __bf16* __restrict__ BT,
                                            unsigned char* __restrict__ C8,
                                            int N, int K, int H,
                                            const float* __restrict__ as_,
                                            const float* __restrict__ ad_,
                                            float* __restrict__ esp,
                                            float* __restrict__ edp,
                                            int t, __bf16* As, __bf16* Bs,
                                            int wave, int lane) {
    int m0 = (t % 80) * 128, n0 = (t / 80) * 128;
    floatx4 acc[2][8] = {};
    gemm_loop<8>(A, BT, K, m0, n0, wave, lane, As, Bs, acc);

    int crow = m0 + wave * 32 + (lane >> 4) * 4;
    int ccol = n0 + (lane & 15);
#pragma unroll
    for (int mt = 0; mt < 2; ++mt)
#pragma unroll
        for (int nt = 0; nt < 8; ++nt)
#pragma unroll
            for (int r = 0; r < 4; ++r) {
                float v = acc[mt][nt][r];
                size_t o = (size_t)(crow + mt * 16 + r) * N + ccol + nt * 16;
                int p = __builtin_amdgcn_cvt_pk_fp8_f32(v, v, 0, false);
                C8[o] = (unsigned char)(p & 0xff);
            }

    int head = n0 >> 7;
    float a_sv[8], a_dv[8];
#pragma unroll
    for (int nt = 0; nt < 8; ++nt) {
        int cin = nt * 16 + (lane & 15);
        a_sv[nt] = as_[head * 128 + cin];
        a_dv[nt] = ad_[head * 128 + cin];
    }
#pragma unroll
    for (int mt = 0; mt < 2; ++mt)
#pragma unroll
        for (int r = 0; r < 4; ++r) {
            float ps = 0.f, pd = 0.f;
#pragma unroll
            for (int nt = 0; nt < 8; ++nt) {
                float v = acc[mt][nt][r];
                ps += v * a_sv[nt];
                pd += v * a_dv[nt];
            }
#pragma unroll
            for (int off = 8; off; off >>= 1) {
                ps += __shfl_xor(ps, off);
                pd += __shfl_xor(pd, off);
            }
            if ((lane & 15) == 0) {
                int row = crow + mt * 16 + r;
                esp[row * H + head] = ps;
                edp[row * H + head] = pd;
            }
        }
}

// standalone gemm_h (layer 2): grid (80, H)
__global__ __launch_bounds__(256) void gemm_h(const __bf16* __restrict__ A,
                                              const __bf16* __restrict__ BT,
                                              unsigned char* __restrict__ C8,
                                              int N, int K, int H,
                                              const float* __restrict__ as_,
                                              const float* __restrict__ ad_,
                                              float* __restrict__ esp,
                                              float* __restrict__ edp) {
    __shared__ __align__(16) __bf16 As[128 * 64];
    __shared__ __align__(16) __bf16 Bs[128 * 64];
    int tid = threadIdx.x, wave = tid >> 6, lane = tid & 63;
    int t = blockIdx.x + 80 * blockIdx.y;
    gemm_h_tile(A, BT, C8, N, K, H, as_, ad_, esp, edp, t, As, Bs, wave, lane);
}

// merged: gemm_h layer 1 (blocks 0..319) + CSR scatter (blocks >= 320).
// Independent work items; scatter hides under the GEMM.
__global__ __launch_bounds__(256) void gemm1s(const __bf16* __restrict__ A,
                                              const __bf16* __restrict__ BT,
                                              unsigned char* __restrict__ C8,
                                              const float* __restrict__ as_,
                                              const float* __restrict__ ad_,
                                              float* __restrict__ esp,
                                              float* __restrict__ edp,
                                              const int* __restrict__ esrc,
                                              const int* __restrict__ edst, int E,
                                              int* __restrict__ cursor,
                                              int* __restrict__ csr) {
    __shared__ __align__(16) __bf16 As[128 * 64];
    __shared__ __align__(16) __bf16 Bs[128 * 64];
    int bid = blockIdx.x;
    if (bid >= 320) {
        int i = (bid - 320) * 256 + threadIdx.x;
        if (i < E) {
            int pos = atomicAdd(&cursor[edst[i]], 1);
            csr[pos] = esrc[i];
        } else if (i < E + N_NODES) {
            int v = i - E;
            int pos = atomicAdd(&cursor[v], 1);
            csr[pos] = v;                              // self-loop
        }
        return;
    }
    int tid = threadIdx.x, wave = tid >> 6, lane = tid & 63;
    gemm_h_tile(A, BT, C8, 512, 512, 4, as_, ad_, esp, edp, bid, As, Bs, wave, lane);
}

// merged: gemm_h layer 3 (blocks 0..79, H=1 N=128) + residual out = xb@WrT + br
// (blocks 80..399). Residual is independent of layers 1-3.
__global__ __launch_bounds__(256) void gemm3r(const __bf16* __restrict__ hb,
                                              const __bf16* __restrict__ W3T,
                                              unsigned char* __restrict__ C8,
                                              const float* __restrict__ a3s,
                                              const float* __restrict__ a3d,
                                              float* __restrict__ esp,
                                              float* __restrict__ edp,
                                              const __bf16* __restrict__ xb,
                                              const __bf16* __restrict__ WrT,
                                              const float* __restrict__ br,
                                              float* __restrict__ out) {
    __shared__ __align__(16) __bf16 As[128 * 64];
    __shared__ __align__(16) __bf16 Bs[128 * 64];
    int tid = threadIdx.x, wave = tid >> 6, lane = tid & 63;
    int bid = blockIdx.x;
    if (bid < 80) {
        gemm_h_tile(hb, W3T, C8, 128, 512, 1, a3s, a3d, esp, edp, bid, As, Bs, wave, lane);
        return;
    }
    int t = bid - 80;
    int m0 = (t % 80) * 128, n0 = (t / 80) * 64;
    floatx4 acc[2][4] = {};
    gemm_loop<4>(xb, WrT, 512, m0, n0, wave, lane, As, Bs, acc);

    int crow = m0 + wave * 32 + (lane >> 4) * 4;
    int ccol = n0 + (lane & 15);
#pragma unroll
    for (int mt = 0; mt < 2; ++mt)
#pragma unroll
        for (int nt = 0; nt < 4; ++nt)
#pragma unroll
            for (int r = 0; r < 4; ++r) {
                int row = crow + mt * 16 + r;
                int col = ccol + nt * 16;
                if (row < N_NODES)
                    out[(size_t)row * 256 + col] = acc[mt][nt][r] + br[col];
            }
}

// final accumulate: out += hb3@WlT^T + bl  (K=128 only)
__global__ __launch_bounds__(256) void gemm_acc(const __bf16* __restrict__ hb3,
                                                const __bf16* __restrict__ WlT,
                                                float* __restrict__ out,
                                                const float* __restrict__ bl) {
    __shared__ __align__(16) __bf16 As[128 * 64];
    __shared__ __align__(16) __bf16 Bs[64 * 64];
    int tid = threadIdx.x, wave = tid >> 6, lane = tid & 63;
    int m0 = blockIdx.x * 128, n0 = blockIdx.y * 64;
    floatx4 acc[2][4] = {};
    gemm_loop<4>(hb3, WlT, 128, m0, n0, wave, lane, As, Bs, acc);

    int crow = m0 + wave * 32 + (lane >> 4) * 4;
    int ccol = n0 + (lane & 15);
#pragma unroll
    for (int mt = 0; mt < 2; ++mt)
#pragma unroll
        for (int nt = 0; nt < 4; ++nt)
#pragma unroll
            for (int r = 0; r < 4; ++r) {
                int row = crow + mt * 16 + r;
                int col = ccol + nt * 16;
                if (row < N_NODES) {
                    size_t o = (size_t)row * 256 + col;
                    out[o] = out[o] + acc[mt][nt][r] + bl[col];
                }
            }
}

// ---------------- fused softmax + weighted gather, fp8 H (R2-proven) ----------------

template <int H>
__global__ __launch_bounds__(256) void gather_agg(const unsigned char* __restrict__ H8,
                                                  const float* __restrict__ esp,
                                                  const float* __restrict__ edp,
                                                  const int* __restrict__ rowptr,
                                                  const int* __restrict__ csr,
                                                  const float* __restrict__ bias,
                                                  __bf16* __restrict__ outb) {
    constexpr int F = H * 128;
    constexpr int CH = F / 64;          // 8 or 2
    __shared__ int   sIdx[4][64];
    __shared__ float sWgt[4][64 * H];
    int wave = threadIdx.x >> 6, lane = threadIdx.x & 63;
    int node = blockIdx.x * 4 + wave;
    if (node >= M_PAD) return;
    __bf16* op = outb + (size_t)node * F + lane * CH;
    if (node >= N_NODES) {
        if (H == 4) { bfrag8 z = {}; *(bfrag8*)op = z; }
        else        { bfrag2 z = {}; *(bfrag2*)op = z; }
        return;
    }
    int hsel = (H == 4) ? (lane >> 4) : 0;
    const unsigned char* hp = H8 + lane * CH;
    int beg = rowptr[node], end = rowptr[node + 1];
    float acc[CH] = {};
    float wsum = 0.f;

    float edv0 = 0.f, edv1 = 0.f, edv2 = 0.f, edv3 = 0.f;
    if (H == 4) {
        float4 e4 = *(const float4*)(edp + node * 4);
        edv0 = e4.x; edv1 = e4.y; edv2 = e4.z; edv3 = e4.w;
    } else {
        edv0 = edp[node];
    }

    for (int t0 = beg; t0 < end; t0 += 64) {
        int n_t = end - t0; if (n_t > 64) n_t = 64;
        // pass 1: one lane per edge, all H logits once
        if (lane < n_t) {
            int s = csr[t0 + lane];
            sIdx[wave][lane] = s;
            if (H == 4) {
                float4 es = *(const float4*)(esp + s * 4);
                float tt0 = es.x + edv0; tt0 = tt0 > 0.f ? tt0 : 0.2f * tt0;
                float tt1 = es.y + edv1; tt1 = tt1 > 0.f ? tt1 : 0.2f * tt1;
                float tt2 = es.z + edv2; tt2 = tt2 > 0.f ? tt2 : 0.2f * tt2;
                float tt3 = es.w + edv3; tt3 = tt3 > 0.f ? tt3 : 0.2f * tt3;
                floatx4 w4 = { __expf(tt0), __expf(tt1), __expf(tt2), __expf(tt3) };
                *(floatx4*)&sWgt[wave][lane * 4] = w4;
            } else {
                float tt = esp[s] + edv0; tt = tt > 0.f ? tt : 0.2f * tt;
                sWgt[wave][lane] = __expf(tt);
            }
        }
        asm volatile("s_waitcnt lgkmcnt(0)" ::: "memory");

        // pass 2: weighted gather, 4-deep pipelined
        int e = 0;
        for (; e + 3 < n_t; e += 4) {
            int s4[4]; float w4[4];
#pragma unroll
            for (int u = 0; u < 4; ++u) {
                s4[u] = sIdx[wave][e + u];
                w4[u] = sWgt[wave][(e + u) * H + hsel];
            }
            if (H == 4) {
                uint2 p4[4];
#pragma unroll
                for (int u = 0; u < 4; ++u) p4[u] = *(const uint2*)(hp + (size_t)s4[u] * F);
#pragma unroll
                for (int u = 0; u < 4; ++u) {
                    float wgt = w4[u];
                    wsum += wgt;
                    floatx2 f0 = __builtin_amdgcn_cvt_pk_f32_fp8(p4[u].x, false);
                    floatx2 f1 = __builtin_amdgcn_cvt_pk_f32_fp8(p4[u].x, true);
                    floatx2 f2 = __builtin_amdgcn_cvt_pk_f32_fp8(p4[u].y, false);
                    floatx2 f3 = __builtin_amdgcn_cvt_pk_f32_fp8(p4[u].y, true);
                    acc[0] += wgt * f0[0]; acc[1] += wgt * f0[1];
                    acc[2] += wgt * f1[0]; acc[3] += wgt * f1[1];
                    acc[4] += wgt * f2[0]; acc[5] += wgt * f2[1];
                    acc[6] += wgt * f3[0]; acc[7] += wgt * f3[1];
                }
            } else {
                unsigned short p4[4];
#pragma unroll
                for (int u = 0; u < 4; ++u) p4[u] = *(const unsigned short*)(hp + (size_t)s4[u] * F);
#pragma unroll
                for (int u = 0; u < 4; ++u) {
                    float wgt = w4[u];
                    wsum += wgt;
                    floatx2 f0 = __builtin_amdgcn_cvt_pk_f32_fp8((int)p4[u], false);
                    acc[0] += wgt * f0[0]; acc[1] += wgt * f0[1];
                }
            }
        }
        for (; e < n_t; ++e) {
            int s0 = sIdx[wave][e];
            float wgt = sWgt[wave][e * H + hsel];
            wsum += wgt;
            if (H == 4) {
                uint2 p = *(const uint2*)(hp + (size_t)s0 * F);
                floatx2 f0 = __builtin_amdgcn_cvt_pk_f32_fp8(p.x, false);
                floatx2 f1 = __builtin_amdgcn_cvt_pk_f32_fp8(p.x, true);
                floatx2 f2 = __builtin_amdgcn_cvt_pk_f32_fp8(p.y, false);
                floatx2 f3 = __builtin_amdgcn_cvt_pk_f32_fp8(p.y, true);
                acc[0] += wgt * f0[0]; acc[1] += wgt * f0[1];
                acc[2] += wgt * f1[0]; acc[3] += wgt * f1[1];
                acc[4] += wgt * f2[0]; acc[5] += wgt * f2[1];
                acc[6] += wgt * f3[0]; acc[7] += wgt * f3[1];
            } else {
                unsigned short p = *(const unsigned short*)(hp + (size_t)s0 * F);
                floatx2 f0 = __builtin_amdgcn_cvt_pk_f32_fp8((int)p, false);
                acc[0] += wgt * f0[0]; acc[1] += wgt * f0[1];
            }
        }
    }

    float inv = 1.f / (wsum + 1e-16f);
    if (H == 4) {
        bfrag8 r;
#pragma unroll
        for (int k = 0; k < 8; ++k) {
            float o = acc[k] * inv + bias[lane * 8 + k];
            o = o > 0.f ? o : __expf(o) - 1.f;     // ELU
            r[k] = (__bf16)o;
        }
        *(bfrag8*)op = r;
    } else {
        bfrag2 r;
#pragma unroll
        for (int k = 0; k < 2; ++k) {
            float o = acc[k] * inv + bias[lane * 2 + k];
            o = o > 0.f ? o : __expf(o) - 1.f;
            r[k] = (__bf16)o;
        }
        *(bfrag2*)op = r;
    }
}

// ---------------- launch ----------------

extern "C" void kernel_launch(void* const* d_in, const int* in_sizes, int n_in,
                              void* d_out, int out_size, void* d_ws, size_t ws_size,
                              hipStream_t stream) {
    const float* x   = (const float*)d_in[0];
    const float* W1  = (const float*)d_in[1];
    const float* a1s = (const float*)d_in[2];
    const float* a1d = (const float*)d_in[3];
    const float* b1  = (const float*)d_in[4];
    const float* W2  = (const float*)d_in[5];
    const float* a2s = (const float*)d_in[6];
    const float* a2d = (const float*)d_in[7];
    const float* b2  = (const float*)d_in[8];
    const float* W3  = (const float*)d_in[9];
    const float* a3s = (const float*)d_in[10];
    const float* a3d = (const float*)d_in[11];
    const float* b3  = (const float*)d_in[12];
    const float* Wl  = (const float*)d_in[13];
    const float* bl  = (const float*)d_in[14];
    const float* Wr  = (const float*)d_in[15];
    const float* br  = (const float*)d_in[16];
    const int*   ei  = (const int*)d_in[17];
    const int E = in_sizes[17] / 2;
    const int* esrc = ei;
    const int* edst = ei + E;
    const int slots = E + N_NODES;
    float* out = (float*)d_out;

    char* w = (char*)d_ws;
    auto alloc = [&](size_t b) { char* p = w; w += (b + 255) & ~(size_t)255; return p; };
    __bf16* xb  = (__bf16*)alloc((size_t)M_PAD * 512 * 2);
    __bf16* hb  = (__bf16*)alloc((size_t)M_PAD * 512 * 2);
    __bf16* hb3 = (__bf16*)alloc((size_t)M_PAD * 128 * 2);
    unsigned char* Hi8 = (unsigned char*)alloc((size_t)M_PAD * 512);
    __bf16* W1T = (__bf16*)alloc(512 * 512 * 2);
    __bf16* W2T = (__bf16*)alloc(512 * 512 * 2);
    __bf16* W3T = (__bf16*)alloc(128 * 512 * 2);
    __bf16* WlT = (__bf16*)alloc(256 * 128 * 2);
    __bf16* WrT = (__bf16*)alloc(256 * 512 * 2);
    float* esp    = (float*)alloc((size_t)M_PAD * HEADS * 4);
    float* edp    = (float*)alloc((size_t)M_PAD * HEADS * 4);
    int*   deg    = (int*)alloc((N_NODES + 1) * 4);    // +1: donecnt
    int*   rowptr = (int*)alloc((N_NODES + 1) * 4);
    int*   cursor = (int*)alloc(N_NODES * 4);
    int*   csr    = (int*)alloc((size_t)slots * 4);

    (void)hipMemsetAsync(deg, 0, (N_NODES + 1) * sizeof(int), stream);

    const int sp_total = S0V + S1E + S2E + S3E + S4E + S5E + E;
    prep<<<(sp_total + 255) / 256, 256, 0, stream>>>(x, W1, W2, W3, Wl, Wr, edst, E,
                                                     xb, W1T, W2T, W3T, WlT, WrT,
                                                     deg, rowptr, cursor, deg + N_NODES);

    const int scat_blocks = (E + N_NODES + 255) / 256;
    // layer 1 GEMM + CSR scatter (independent, one dispatch)
    gemm1s<<<320 + scat_blocks, 256, 0, stream>>>(xb, W1T, Hi8, a1s, a1d, esp, edp,
                                                  esrc, edst, E, cursor, csr);
    gather_agg<4><<<M_PAD / 4, 256, 0, stream>>>(Hi8, esp, edp, rowptr, csr, b1, hb);
    // layer 2
    gemm_h<<<dim3(80, 4), 256, 0, stream>>>(hb, W2T, Hi8, 512, 512, 4,
                                            a2s, a2d, esp, edp);
    gather_agg<4><<<M_PAD / 4, 256, 0, stream>>>(Hi8, esp, edp, rowptr, csr, b2, hb);
    // layer 3 (H=1) + residual out = xb@WrT + br (independent, one dispatch)
    gemm3r<<<400, 256, 0, stream>>>(hb, W3T, Hi8, a3s, a3d, esp, edp,
                                    xb, WrT, br, out);
    gather_agg<1><<<M_PAD / 4, 256, 0, stream>>>(Hi8, esp, edp, rowptr, csr, b3, hb3);
    // final: out += hb3@WlT + bl (K=128)
    gemm_acc<<<dim3(80, 4), 256, 0, stream>>>(hb3, WlT, out, bl);
}

// Round 5
// 236.102 us; speedup vs baseline: 2.7848x; 2.5558x over previous
//
#include <hip/hip_runtime.h>
#include <hip/hip_bf16.h>
#include <cstdint>
#include <cstddef>

#define N_NODES 10000
#define M_PAD   10240   // 80 panels of 128; 80 % 8 == 0 -> panel%8 = XCD under round-robin
#define HEADS   4

typedef __bf16 bfrag8 __attribute__((ext_vector_type(8)));
typedef __bf16 bfrag2 __attribute__((ext_vector_type(2)));
typedef float  floatx4 __attribute__((ext_vector_type(4)));
typedef float  floatx2 __attribute__((ext_vector_type(2)));

#define S0V (M_PAD * 512 / 8)   // xb
#define S1E (512 * 512 / 8)     // W1T
#define S2E (512 * 512 / 8)     // W2T
#define S3E (512 * 128 / 8)     // W3T
#define S4E (128 * 256 / 8)     // WlT
#define S5E (512 * 256 / 8)     // WrT

// ---------------- prep: x->bf16 pad, 5 weight transposes, degree count.
// NO tail work: __threadfence() in a wide kernel costs ~400us (R4 lesson). ----

__global__ __launch_bounds__(256) void prep(const float* __restrict__ x,
                                            const float* __restrict__ W1,
                                            const float* __restrict__ W2,
                                            const float* __restrict__ W3,
                                            const float* __restrict__ Wl,
                                            const float* __restrict__ Wr,
                                            const int* __restrict__ edst, int E,
                                            __bf16* __restrict__ xb,
                                            __bf16* __restrict__ W1T,
                                            __bf16* __restrict__ W2T,
                                            __bf16* __restrict__ W3T,
                                            __bf16* __restrict__ WlT,
                                            __bf16* __restrict__ WrT,
                                            int* __restrict__ deg) {
    int i = blockIdx.x * 256 + threadIdx.x;
    if (i < S0V) {
        int base = i * 8;
        int row = base >> 9;
        bfrag8 r = {};
        if (row < N_NODES) {
            float4 f0 = ((const float4*)x)[i * 2];
            float4 f1 = ((const float4*)x)[i * 2 + 1];
            r[0] = (__bf16)f0.x; r[1] = (__bf16)f0.y; r[2] = (__bf16)f0.z; r[3] = (__bf16)f0.w;
            r[4] = (__bf16)f1.x; r[5] = (__bf16)f1.y; r[6] = (__bf16)f1.z; r[7] = (__bf16)f1.w;
        }
        *(bfrag8*)(xb + base) = r;
    } else if ((i -= S0V) < S1E) {          // W1: K=512, N=512
        int n = i & 511, kb = (i >> 9) * 8;
        bfrag8 r;
#pragma unroll
        for (int t = 0; t < 8; ++t) r[t] = (__bf16)W1[(kb + t) * 512 + n];
        *(bfrag8*)(W1T + n * 512 + kb) = r;
    } else if ((i -= S1E) < S2E) {          // W2
        int n = i & 511, kb = (i >> 9) * 8;
        bfrag8 r;
#pragma unroll
        for (int t = 0; t < 8; ++t) r[t] = (__bf16)W2[(kb + t) * 512 + n];
        *(bfrag8*)(W2T + n * 512 + kb) = r;
    } else if ((i -= S2E) < S3E) {          // W3: K=512, N=128
        int n = i & 127, kb = (i >> 7) * 8;
        bfrag8 r;
#pragma unroll
        for (int t = 0; t < 8; ++t) r[t] = (__bf16)W3[(kb + t) * 128 + n];
        *(bfrag8*)(W3T + n * 512 + kb) = r;
    } else if ((i -= S3E) < S4E) {          // Wl: K=128, N=256
        int n = i & 255, kb = (i >> 8) * 8;
        bfrag8 r;
#pragma unroll
        for (int t = 0; t < 8; ++t) r[t] = (__bf16)Wl[(kb + t) * 256 + n];
        *(bfrag8*)(WlT + n * 128 + kb) = r;
    } else if ((i -= S4E) < S5E) {          // Wr: K=512, N=256
        int n = i & 255, kb = (i >> 8) * 8;
        bfrag8 r;
#pragma unroll
        for (int t = 0; t < 8; ++t) r[t] = (__bf16)Wr[(kb + t) * 256 + n];
        *(bfrag8*)(WrT + n * 512 + kb) = r;
    } else if ((i -= S5E) < E) {
        atomicAdd(&deg[edst[i]], 1);
    }
}

// ---------------- CSR scan: 1024 threads, chunk=10 rows/thread (R2-proven) ----

__global__ __launch_bounds__(1024) void scan_kernel(const int* __restrict__ deg,
                                                    int* __restrict__ rowptr,
                                                    int* __restrict__ cursor, int n) {
    __shared__ int wtot[16], woff[16];
    int t = threadIdx.x, lane = t & 63, wv = t >> 6;
    int chunk = (n + 1023) / 1024;
    int beg = t * chunk, end = beg + chunk; if (end > n) end = n; if (beg > n) beg = n;
    int s = 0;
    for (int i = beg; i < end; ++i) s += deg[i] + 1;   // +1 self-loop
    int v = s;
#pragma unroll
    for (int off = 1; off < 64; off <<= 1) {
        int o = __shfl_up(v, off);
        if (lane >= off) v += o;
    }
    if (lane == 63) wtot[wv] = v;
    __syncthreads();
    if (t == 0) {
        int r = 0;
#pragma unroll
        for (int i = 0; i < 16; ++i) { woff[i] = r; r += wtot[i]; }
        rowptr[n] = r;
    }
    __syncthreads();
    int off = woff[wv] + v - s;     // exclusive prefix
    for (int i = beg; i < end; ++i) {
        rowptr[i] = off; cursor[i] = off;
        off += deg[i] + 1;
    }
}

// ---------------- MFMA GEMM K-loop, BK=64, tile 128(M) x 16*NT(N) ----------------

template <int NT>
__device__ __forceinline__ void gemm_loop(const __bf16* __restrict__ A,
                                          const __bf16* __restrict__ BT, int K,
                                          int m0, int n0, int wave, int lane,
                                          __bf16* As, __bf16* Bs,
                                          floatx4 (&acc)[2][NT]) {
    int r = wave * 8 + (lane >> 3);          // 0..31 staging row
    int kof = (lane & 7) * 8;
    const __bf16* gA = A + (size_t)(m0 + r) * K + kof;
    const __bf16* gB = BT + (size_t)(n0 + r) * K + kof;
    __bf16* lA = As + r * 64 + kof;
    __bf16* lB = Bs + r * 64 + kof;
    const __bf16* fA = As + (wave * 32 + (lane & 15)) * 64 + (lane >> 4) * 8;
    const __bf16* fB = Bs + (lane & 15) * 64 + (lane >> 4) * 8;

    for (int k0 = 0; k0 < K; k0 += 64) {
#pragma unroll
        for (int u = 0; u < 4; ++u)
            __builtin_amdgcn_global_load_lds(
                (const __attribute__((address_space(1))) void*)(gA + (size_t)u * 32 * K),
                (__attribute__((address_space(3))) void*)(lA + u * 32 * 64), 16, 0, 0);
#pragma unroll
        for (int u = 0; u < NT / 2; ++u)
            __builtin_amdgcn_global_load_lds(
                (const __attribute__((address_space(1))) void*)(gB + (size_t)u * 32 * K),
                (__attribute__((address_space(3))) void*)(lB + u * 32 * 64), 16, 0, 0);
        gA += 64; gB += 64;
        __syncthreads();

#pragma unroll
        for (int ks = 0; ks < 2; ++ks) {
            bfrag8 a0 = *(const bfrag8*)(fA + ks * 32);
            bfrag8 a1 = *(const bfrag8*)(fA + 16 * 64 + ks * 32);
#pragma unroll
            for (int nt = 0; nt < NT; ++nt) {
                bfrag8 b = *(const bfrag8*)(fB + nt * 16 * 64 + ks * 32);
                acc[0][nt] = __builtin_amdgcn_mfma_f32_16x16x32_bf16(a0, b, acc[0][nt], 0, 0, 0);
                acc[1][nt] = __builtin_amdgcn_mfma_f32_16x16x32_bf16(a1, b, acc[1][nt], 0, 0, 0);
            }
        }
        __syncthreads();
    }
}

// one 128x128 tile of H = A@B^T, fp8 out + fused logit sums (full head per tile)
__device__ __forceinline__ void gemm_h_tile(const __bf16* __restrict__ A,
                                            const __bf16* __restrict__ BT,
                                            unsigned char* __restrict__ C8,
                                            int N, int K, int H,
                                            const float* __restrict__ as_,
                                            const float* __restrict__ ad_,
                                            float* __restrict__ esp,
                                            float* __restrict__ edp,
                                            int t, __bf16* As, __bf16* Bs,
                                            int wave, int lane) {
    int m0 = (t % 80) * 128, n0 = (t / 80) * 128;
    floatx4 acc[2][8] = {};
    gemm_loop<8>(A, BT, K, m0, n0, wave, lane, As, Bs, acc);

    int crow = m0 + wave * 32 + (lane >> 4) * 4;
    int ccol = n0 + (lane & 15);
#pragma unroll
    for (int mt = 0; mt < 2; ++mt)
#pragma unroll
        for (int nt = 0; nt < 8; ++nt)
#pragma unroll
            for (int r = 0; r < 4; ++r) {
                float v = acc[mt][nt][r];
                size_t o = (size_t)(crow + mt * 16 + r) * N + ccol + nt * 16;
                int p = __builtin_amdgcn_cvt_pk_fp8_f32(v, v, 0, false);
                C8[o] = (unsigned char)(p & 0xff);
            }

    int head = n0 >> 7;
    float a_sv[8], a_dv[8];
#pragma unroll
    for (int nt = 0; nt < 8; ++nt) {
        int cin = nt * 16 + (lane & 15);
        a_sv[nt] = as_[head * 128 + cin];
        a_dv[nt] = ad_[head * 128 + cin];
    }
#pragma unroll
    for (int mt = 0; mt < 2; ++mt)
#pragma unroll
        for (int r = 0; r < 4; ++r) {
            float ps = 0.f, pd = 0.f;
#pragma unroll
            for (int nt = 0; nt < 8; ++nt) {
                float v = acc[mt][nt][r];
                ps += v * a_sv[nt];
                pd += v * a_dv[nt];
            }
#pragma unroll
            for (int off = 8; off; off >>= 1) {
                ps += __shfl_xor(ps, off);
                pd += __shfl_xor(pd, off);
            }
            if ((lane & 15) == 0) {
                int row = crow + mt * 16 + r;
                esp[row * H + head] = ps;
                edp[row * H + head] = pd;
            }
        }
}

// standalone gemm_h (layer 2): grid (80, H)
__global__ __launch_bounds__(256) void gemm_h(const __bf16* __restrict__ A,
                                              const __bf16* __restrict__ BT,
                                              unsigned char* __restrict__ C8,
                                              int N, int K, int H,
                                              const float* __restrict__ as_,
                                              const float* __restrict__ ad_,
                                              float* __restrict__ esp,
                                              float* __restrict__ edp) {
    __shared__ __align__(16) __bf16 As[128 * 64];
    __shared__ __align__(16) __bf16 Bs[128 * 64];
    int tid = threadIdx.x, wave = tid >> 6, lane = tid & 63;
    int t = blockIdx.x + 80 * blockIdx.y;
    gemm_h_tile(A, BT, C8, N, K, H, as_, ad_, esp, edp, t, As, Bs, wave, lane);
}

// merged: gemm_h layer 1 (blocks 0..319) + CSR scatter (blocks >= 320).
// Independent work items; scatter hides under the GEMM.
__global__ __launch_bounds__(256) void gemm1s(const __bf16* __restrict__ A,
                                              const __bf16* __restrict__ BT,
                                              unsigned char* __restrict__ C8,
                                              const float* __restrict__ as_,
                                              const float* __restrict__ ad_,
                                              float* __restrict__ esp,
                                              float* __restrict__ edp,
                                              const int* __restrict__ esrc,
                                              const int* __restrict__ edst, int E,
                                              int* __restrict__ cursor,
                                              int* __restrict__ csr) {
    __shared__ __align__(16) __bf16 As[128 * 64];
    __shared__ __align__(16) __bf16 Bs[128 * 64];
    int bid = blockIdx.x;
    if (bid >= 320) {
        int i = (bid - 320) * 256 + threadIdx.x;
        if (i < E) {
            int pos = atomicAdd(&cursor[edst[i]], 1);
            csr[pos] = esrc[i];
        } else if (i < E + N_NODES) {
            int v = i - E;
            int pos = atomicAdd(&cursor[v], 1);
            csr[pos] = v;                              // self-loop
        }
        return;
    }
    int tid = threadIdx.x, wave = tid >> 6, lane = tid & 63;
    gemm_h_tile(A, BT, C8, 512, 512, 4, as_, ad_, esp, edp, bid, As, Bs, wave, lane);
}

// merged: gemm_h layer 3 (blocks 0..79, H=1 N=128) + residual out = xb@WrT + br
// (blocks 80..399). Residual is independent of layers 1-3.
__global__ __launch_bounds__(256) void gemm3r(const __bf16* __restrict__ hb,
                                              const __bf16* __restrict__ W3T,
                                              unsigned char* __restrict__ C8,
                                              const float* __restrict__ a3s,
                                              const float* __restrict__ a3d,
                                              float* __restrict__ esp,
                                              float* __restrict__ edp,
                                              const __bf16* __restrict__ xb,
                                              const __bf16* __restrict__ WrT,
                                              const float* __restrict__ br,
                                              float* __restrict__ out) {
    __shared__ __align__(16) __bf16 As[128 * 64];
    __shared__ __align__(16) __bf16 Bs[128 * 64];
    int tid = threadIdx.x, wave = tid >> 6, lane = tid & 63;
    int bid = blockIdx.x;
    if (bid < 80) {
        gemm_h_tile(hb, W3T, C8, 128, 512, 1, a3s, a3d, esp, edp, bid, As, Bs, wave, lane);
        return;
    }
    int t = bid - 80;
    int m0 = (t % 80) * 128, n0 = (t / 80) * 64;
    floatx4 acc[2][4] = {};
    gemm_loop<4>(xb, WrT, 512, m0, n0, wave, lane, As, Bs, acc);

    int crow = m0 + wave * 32 + (lane >> 4) * 4;
    int ccol = n0 + (lane & 15);
#pragma unroll
    for (int mt = 0; mt < 2; ++mt)
#pragma unroll
        for (int nt = 0; nt < 4; ++nt)
#pragma unroll
            for (int r = 0; r < 4; ++r) {
                int row = crow + mt * 16 + r;
                int col = ccol + nt * 16;
                if (row < N_NODES)
                    out[(size_t)row * 256 + col] = acc[mt][nt][r] + br[col];
            }
}

// final accumulate: out += hb3@WlT^T + bl  (K=128 only)
__global__ __launch_bounds__(256) void gemm_acc(const __bf16* __restrict__ hb3,
                                                const __bf16* __restrict__ WlT,
                                                float* __restrict__ out,
                                                const float* __restrict__ bl) {
    __shared__ __align__(16) __bf16 As[128 * 64];
    __shared__ __align__(16) __bf16 Bs[64 * 64];
    int tid = threadIdx.x, wave = tid >> 6, lane = tid & 63;
    int m0 = blockIdx.x * 128, n0 = blockIdx.y * 64;
    floatx4 acc[2][4] = {};
    gemm_loop<4>(hb3, WlT, 128, m0, n0, wave, lane, As, Bs, acc);

    int crow = m0 + wave * 32 + (lane >> 4) * 4;
    int ccol = n0 + (lane & 15);
#pragma unroll
    for (int mt = 0; mt < 2; ++mt)
#pragma unroll
        for (int nt = 0; nt < 4; ++nt)
#pragma unroll
            for (int r = 0; r < 4; ++r) {
                int row = crow + mt * 16 + r;
                int col = ccol + nt * 16;
                if (row < N_NODES) {
                    size_t o = (size_t)row * 256 + col;
                    out[o] = out[o] + acc[mt][nt][r] + bl[col];
                }
            }
}

// ---------------- fused softmax + weighted gather, fp8 H (R2-proven) ----------------

template <int H>
__global__ __launch_bounds__(256) void gather_agg(const unsigned char* __restrict__ H8,
                                                  const float* __restrict__ esp,
                                                  const float* __restrict__ edp,
                                                  const int* __restrict__ rowptr,
                                                  const int* __restrict__ csr,
                                                  const float* __restrict__ bias,
                                                  __bf16* __restrict__ outb) {
    constexpr int F = H * 128;
    constexpr int CH = F / 64;          // 8 or 2
    __shared__ int   sIdx[4][64];
    __shared__ float sWgt[4][64 * H];
    int wave = threadIdx.x >> 6, lane = threadIdx.x & 63;
    int node = blockIdx.x * 4 + wave;
    if (node >= M_PAD) return;
    __bf16* op = outb + (size_t)node * F + lane * CH;
    if (node >= N_NODES) {
        if (H == 4) { bfrag8 z = {}; *(bfrag8*)op = z; }
        else        { bfrag2 z = {}; *(bfrag2*)op = z; }
        return;
    }
    int hsel = (H == 4) ? (lane >> 4) : 0;
    const unsigned char* hp = H8 + lane * CH;
    int beg = rowptr[node], end = rowptr[node + 1];
    float acc[CH] = {};
    float wsum = 0.f;

    float edv0 = 0.f, edv1 = 0.f, edv2 = 0.f, edv3 = 0.f;
    if (H == 4) {
        float4 e4 = *(const float4*)(edp + node * 4);
        edv0 = e4.x; edv1 = e4.y; edv2 = e4.z; edv3 = e4.w;
    } else {
        edv0 = edp[node];
    }

    for (int t0 = beg; t0 < end; t0 += 64) {
        int n_t = end - t0; if (n_t > 64) n_t = 64;
        // pass 1: one lane per edge, all H logits once
        if (lane < n_t) {
            int s = csr[t0 + lane];
            sIdx[wave][lane] = s;
            if (H == 4) {
                float4 es = *(const float4*)(esp + s * 4);
                float tt0 = es.x + edv0; tt0 = tt0 > 0.f ? tt0 : 0.2f * tt0;
                float tt1 = es.y + edv1; tt1 = tt1 > 0.f ? tt1 : 0.2f * tt1;
                float tt2 = es.z + edv2; tt2 = tt2 > 0.f ? tt2 : 0.2f * tt2;
                float tt3 = es.w + edv3; tt3 = tt3 > 0.f ? tt3 : 0.2f * tt3;
                floatx4 w4 = { __expf(tt0), __expf(tt1), __expf(tt2), __expf(tt3) };
                *(floatx4*)&sWgt[wave][lane * 4] = w4;
            } else {
                float tt = esp[s] + edv0; tt = tt > 0.f ? tt : 0.2f * tt;
                sWgt[wave][lane] = __expf(tt);
            }
        }
        asm volatile("s_waitcnt lgkmcnt(0)" ::: "memory");

        // pass 2: weighted gather, 4-deep pipelined
        int e = 0;
        for (; e + 3 < n_t; e += 4) {
            int s4[4]; float w4[4];
#pragma unroll
            for (int u = 0; u < 4; ++u) {
                s4[u] = sIdx[wave][e + u];
                w4[u] = sWgt[wave][(e + u) * H + hsel];
            }
            if (H == 4) {
                uint2 p4[4];
#pragma unroll
                for (int u = 0; u < 4; ++u) p4[u] = *(const uint2*)(hp + (size_t)s4[u] * F);
#pragma unroll
                for (int u = 0; u < 4; ++u) {
                    float wgt = w4[u];
                    wsum += wgt;
                    floatx2 f0 = __builtin_amdgcn_cvt_pk_f32_fp8(p4[u].x, false);
                    floatx2 f1 = __builtin_amdgcn_cvt_pk_f32_fp8(p4[u].x, true);
                    floatx2 f2 = __builtin_amdgcn_cvt_pk_f32_fp8(p4[u].y, false);
                    floatx2 f3 = __builtin_amdgcn_cvt_pk_f32_fp8(p4[u].y, true);
                    acc[0] += wgt * f0[0]; acc[1] += wgt * f0[1];
                    acc[2] += wgt * f1[0]; acc[3] += wgt * f1[1];
                    acc[4] += wgt * f2[0]; acc[5] += wgt * f2[1];
                    acc[6] += wgt * f3[0]; acc[7] += wgt * f3[1];
                }
            } else {
                unsigned short p4[4];
#pragma unroll
                for (int u = 0; u < 4; ++u) p4[u] = *(const unsigned short*)(hp + (size_t)s4[u] * F);
#pragma unroll
                for (int u = 0; u < 4; ++u) {
                    float wgt = w4[u];
                    wsum += wgt;
                    floatx2 f0 = __builtin_amdgcn_cvt_pk_f32_fp8((int)p4[u], false);
                    acc[0] += wgt * f0[0]; acc[1] += wgt * f0[1];
                }
            }
        }
        for (; e < n_t; ++e) {
            int s0 = sIdx[wave][e];
            float wgt = sWgt[wave][e * H + hsel];
            wsum += wgt;
            if (H == 4) {
                uint2 p = *(const uint2*)(hp + (size_t)s0 * F);
                floatx2 f0 = __builtin_amdgcn_cvt_pk_f32_fp8(p.x, false);
                floatx2 f1 = __builtin_amdgcn_cvt_pk_f32_fp8(p.x, true);
                floatx2 f2 = __builtin_amdgcn_cvt_pk_f32_fp8(p.y, false);
                floatx2 f3 = __builtin_amdgcn_cvt_pk_f32_fp8(p.y, true);
                acc[0] += wgt * f0[0]; acc[1] += wgt * f0[1];
                acc[2] += wgt * f1[0]; acc[3] += wgt * f1[1];
                acc[4] += wgt * f2[0]; acc[5] += wgt * f2[1];
                acc[6] += wgt * f3[0]; acc[7] += wgt * f3[1];
            } else {
                unsigned short p = *(const unsigned short*)(hp + (size_t)s0 * F);
                floatx2 f0 = __builtin_amdgcn_cvt_pk_f32_fp8((int)p, false);
                acc[0] += wgt * f0[0]; acc[1] += wgt * f0[1];
            }
        }
    }

    float inv = 1.f / (wsum + 1e-16f);
    if (H == 4) {
        bfrag8 r;
#pragma unroll
        for (int k = 0; k < 8; ++k) {
            float o = acc[k] * inv + bias[lane * 8 + k];
            o = o > 0.f ? o : __expf(o) - 1.f;     // ELU
            r[k] = (__bf16)o;
        }
        *(bfrag8*)op = r;
    } else {
        bfrag2 r;
#pragma unroll
        for (int k = 0; k < 2; ++k) {
            float o = acc[k] * inv + bias[lane * 2 + k];
            o = o > 0.f ? o : __expf(o) - 1.f;
            r[k] = (__bf16)o;
        }
        *(bfrag2*)op = r;
    }
}

// ---------------- launch ----------------

extern "C" void kernel_launch(void* const* d_in, const int* in_sizes, int n_in,
                              void* d_out, int out_size, void* d_ws, size_t ws_size,
                              hipStream_t stream) {
    const float* x   = (const float*)d_in[0];
    const float* W1  = (const float*)d_in[1];
    const float* a1s = (const float*)d_in[2];
    const float* a1d = (const float*)d_in[3];
    const float* b1  = (const float*)d_in[4];
    const float* W2  = (const float*)d_in[5];
    const float* a2s = (const float*)d_in[6];
    const float* a2d = (const float*)d_in[7];
    const float* b2  = (const float*)d_in[8];
    const float* W3  = (const float*)d_in[9];
    const float* a3s = (const float*)d_in[10];
    const float* a3d = (const float*)d_in[11];
    const float* b3  = (const float*)d_in[12];
    const float* Wl  = (const float*)d_in[13];
    const float* bl  = (const float*)d_in[14];
    const float* Wr  = (const float*)d_in[15];
    const float* br  = (const float*)d_in[16];
    const int*   ei  = (const int*)d_in[17];
    const int E = in_sizes[17] / 2;
    const int* esrc = ei;
    const int* edst = ei + E;
    const int slots = E + N_NODES;
    float* out = (float*)d_out;

    char* w = (char*)d_ws;
    auto alloc = [&](size_t b) { char* p = w; w += (b + 255) & ~(size_t)255; return p; };
    __bf16* xb  = (__bf16*)alloc((size_t)M_PAD * 512 * 2);
    __bf16* hb  = (__bf16*)alloc((size_t)M_PAD * 512 * 2);
    __bf16* hb3 = (__bf16*)alloc((size_t)M_PAD * 128 * 2);
    unsigned char* Hi8 = (unsigned char*)alloc((size_t)M_PAD * 512);
    __bf16* W1T = (__bf16*)alloc(512 * 512 * 2);
    __bf16* W2T = (__bf16*)alloc(512 * 512 * 2);
    __bf16* W3T = (__bf16*)alloc(128 * 512 * 2);
    __bf16* WlT = (__bf16*)alloc(256 * 128 * 2);
    __bf16* WrT = (__bf16*)alloc(256 * 512 * 2);
    float* esp    = (float*)alloc((size_t)M_PAD * HEADS * 4);
    float* edp    = (float*)alloc((size_t)M_PAD * HEADS * 4);
    int*   deg    = (int*)alloc(N_NODES * 4);
    int*   rowptr = (int*)alloc((N_NODES + 1) * 4);
    int*   cursor = (int*)alloc(N_NODES * 4);
    int*   csr    = (int*)alloc((size_t)slots * 4);

    (void)hipMemsetAsync(deg, 0, N_NODES * sizeof(int), stream);

    const int sp_total = S0V + S1E + S2E + S3E + S4E + S5E + E;
    prep<<<(sp_total + 255) / 256, 256, 0, stream>>>(x, W1, W2, W3, Wl, Wr, edst, E,
                                                     xb, W1T, W2T, W3T, WlT, WrT, deg);
    scan_kernel<<<1, 1024, 0, stream>>>(deg, rowptr, cursor, N_NODES);

    const int scat_blocks = (E + N_NODES + 255) / 256;
    // layer 1 GEMM + CSR scatter (independent, one dispatch)
    gemm1s<<<320 + scat_blocks, 256, 0, stream>>>(xb, W1T, Hi8, a1s, a1d, esp, edp,
                                                  esrc, edst, E, cursor, csr);
    gather_agg<4><<<M_PAD / 4, 256, 0, stream>>>(Hi8, esp, edp, rowptr, csr, b1, hb);
    // layer 2
    gemm_h<<<dim3(80, 4), 256, 0, stream>>>(hb, W2T, Hi8, 512, 512, 4,
                                            a2s, a2d, esp, edp);
    gather_agg<4><<<M_PAD / 4, 256, 0, stream>>>(Hi8, esp, edp, rowptr, csr, b2, hb);
    // layer 3 (H=1) + residual out = xb@WrT + br (independent, one dispatch)
    gemm3r<<<400, 256, 0, stream>>>(hb, W3T, Hi8, a3s, a3d, esp, edp,
                                    xb, WrT, br, out);
    gather_agg<1><<<M_PAD / 4, 256, 0, stream>>>(Hi8, esp, edp, rowptr, csr, b3, hb3);
    // final: out += hb3@WlT + bl (K=128)
    gemm_acc<<<dim3(80, 4), 256, 0, stream>>>(hb3, WlT, out, bl);
}